// Round 1
// baseline (2361.565 us; speedup 1.0000x reference)
//
#include <hip/hip_runtime.h>
#include <stdint.h>

#define NIMG 64
#define H 512
#define W 512
#define NPIX (H * W)        // 262144 per image
#define NB 65536            // buckets per image
#define LOGW 9

// ---- NMS: returns post-suppression value for pixel p of one image ----
__device__ __forceinline__ float compute_jm(const float* __restrict__ base,
                                            int p, int y, int x) {
    float c = base[p];
    float nmax = -3.402823466e38f;
    bool ym = (y > 0), yp = (y < H - 1), xm = (x > 0), xp = (x < W - 1);
    if (ym) {
        const float* r = base + (p - W);
        if (xm) nmax = fmaxf(nmax, r[-1]);
        nmax = fmaxf(nmax, r[0]);
        if (xp) nmax = fmaxf(nmax, r[1]);
    }
    {
        const float* r = base + p;
        if (xm) nmax = fmaxf(nmax, r[-1]);
        if (xp) nmax = fmaxf(nmax, r[1]);
    }
    if (yp) {
        const float* r = base + (p + W);
        if (xm) nmax = fmaxf(nmax, r[-1]);
        nmax = fmaxf(nmax, r[0]);
        if (xp) nmax = fmaxf(nmax, r[1]);
    }
    return (nmax >= c) ? 0.6f * c : c;   // matches jnp.where(nmax >= hm, 0.6*hm, hm)
}

__device__ __forceinline__ int bucket_of(float s) {
    int braw = (int)(s * 65536.0f);      // s in [0,1); monotone non-decreasing
    braw = braw > 65535 ? 65535 : braw;  // guard rounding to 65536.0f
    return 65535 - braw;                 // ascending bucket = descending score
}

// ---- K1: NMS + per-image bucket histogram ----
__global__ __launch_bounds__(256) void k1_nms_hist(const float* __restrict__ hm,
                                                   unsigned int* __restrict__ hist) {
    int gid = blockIdx.x * 256 + threadIdx.x;       // [0, NIMG*NPIX)
    int img = gid >> 18;
    int p = gid & (NPIX - 1);
    int y = p >> LOGW;
    int x = p & (W - 1);
    const float* base = hm + (size_t)img * NPIX;
    float jm = compute_jm(base, p, y, x);
    int b = bucket_of(jm);
    atomicAdd(&hist[(size_t)img * NB + b], 1u);
}

// ---- K2: per-image exclusive scan of 65536 bins (in place) ----
__global__ __launch_bounds__(256) void k2_scan(unsigned int* __restrict__ hist) {
    int img = blockIdx.x;
    int t = threadIdx.x;
    unsigned int* hbase = hist + (size_t)img * NB;
    const int CHUNK = NB / 256;                     // 256 bins/thread
    int b0 = t * CHUNK;
    unsigned int s = 0;
    for (int i = 0; i < CHUNK; ++i) s += hbase[b0 + i];
    __shared__ unsigned int sums[256];
    sums[t] = s;
    __syncthreads();
    if (t == 0) {
        unsigned int run = 0;
        for (int i = 0; i < 256; ++i) { unsigned int v = sums[i]; sums[i] = run; run += v; }
    }
    __syncthreads();
    unsigned int run = sums[t];
    for (int i = 0; i < CHUNK; ++i) {
        unsigned int v = hbase[b0 + i];
        hbase[b0 + i] = run;                        // exclusive prefix = bucket start
        run += v;
    }
}

// ---- K3: scatter packed keys into bucket regions (offs becomes bucket ENDs) ----
__global__ __launch_bounds__(256) void k3_scatter(const float* __restrict__ hm,
                                                  unsigned int* __restrict__ offs,
                                                  unsigned long long* __restrict__ sorted) {
    int gid = blockIdx.x * 256 + threadIdx.x;
    int img = gid >> 18;
    int p = gid & (NPIX - 1);
    int y = p >> LOGW;
    int x = p & (W - 1);
    const float* base = hm + (size_t)img * NPIX;
    float jm = compute_jm(base, p, y, x);
    int b = bucket_of(jm);
    unsigned int bits = __float_as_uint(jm);
    // ascending packed == descending score, ties -> ascending pixel index (stable)
    unsigned long long packed = ((unsigned long long)(~bits) << 32) | (unsigned int)p;
    unsigned int pos = atomicAdd(&offs[(size_t)img * NB + b], 1u);
    sorted[(size_t)img * NPIX + pos] = packed;
}

// ---- K4: rank within bucket + gather offsets + emit (cy, cx, score) rows ----
__global__ __launch_bounds__(256) void k4_finalize(const unsigned long long* __restrict__ sorted,
                                                   const unsigned int* __restrict__ offs,
                                                   const float* __restrict__ offset,
                                                   float* __restrict__ out) {
    int gid = blockIdx.x * 256 + threadIdx.x;
    int img = gid >> 18;
    int p = gid & (NPIX - 1);
    const unsigned long long* sbase = sorted + (size_t)img * NPIX;
    unsigned long long packed = sbase[p];
    unsigned int bits = ~(unsigned int)(packed >> 32);
    float score = __uint_as_float(bits);
    int b = bucket_of(score);
    const unsigned int* obase = offs + (size_t)img * NB;
    unsigned int start = (b == 0) ? 0u : obase[b - 1]; // end of prev bucket = start
    unsigned int end = obase[b];
    int rank = 0;
    for (unsigned int q = start; q < end; ++q)
        rank += (sbase[q] < packed) ? 1 : 0;           // keys unique -> exact rank
    unsigned int p0 = (unsigned int)(packed & 0xFFFFFFFFull);
    int yy = (int)(p0 >> LOGW);
    int xx = (int)(p0 & (W - 1));
    const float* ob = offset + (size_t)img * 2 * NPIX;
    float yo = ob[NPIX + p0];                          // offset[img][1] -> y-offset
    float xo = ob[p0];                                 // offset[img][0] -> x-offset
    float cy = (float)yy + yo + 0.5f;
    float cx = (float)xx + xo + 0.5f;
    size_t orow = ((size_t)img * NPIX + start + (unsigned int)rank) * 3;
    out[orow + 0] = cy;
    out[orow + 1] = cx;
    out[orow + 2] = score;
}

extern "C" void kernel_launch(void* const* d_in, const int* in_sizes, int n_in,
                              void* d_out, int out_size, void* d_ws, size_t ws_size,
                              hipStream_t stream) {
    const float* hm = (const float*)d_in[0];       // [64, 512, 512] f32
    const float* offset = (const float*)d_in[1];   // [64, 2, 512, 512] f32
    float* out = (float*)d_out;                    // [64, 262144, 3] f32

    unsigned int* hist = (unsigned int*)d_ws;                              // 16 MB
    unsigned long long* sorted =
        (unsigned long long*)((char*)d_ws + (size_t)NIMG * NB * sizeof(unsigned int)); // 134 MB

    hipMemsetAsync(hist, 0, (size_t)NIMG * NB * sizeof(unsigned int), stream);

    const int total = NIMG * NPIX;                 // 16,777,216
    const int nblk = total / 256;                  // 65536
    k1_nms_hist<<<nblk, 256, 0, stream>>>(hm, hist);
    k2_scan<<<NIMG, 256, 0, stream>>>(hist);
    k3_scatter<<<nblk, 256, 0, stream>>>(hm, hist, sorted);
    k4_finalize<<<nblk, 256, 0, stream>>>(sorted, hist, offset, out);
}

// Round 2
// 841.549 us; speedup vs baseline: 2.8062x; 2.8062x over previous
//
#include <hip/hip_runtime.h>
#include <stdint.h>

#define NIMG 64
#define H 512
#define W 512
#define NPIX (H * W)          // 262144 per image
#define LOGW 9
#define NC 256                 // coarse buckets (top 8 of 16 bucket bits)
#define BLK_ELEMS 4096         // elements per partition block
#define BLOCKS_PER_IMG (NPIX / BLK_ELEMS)   // 64
#define NPART (NIMG * BLOCKS_PER_IMG)       // 4096
#define SEGCAP 2048            // max segment len handled in LDS (density max ~1707, 8σ≈2040; fallback below)

typedef unsigned int uint32;
typedef unsigned long long ull;

// ---- NMS: post-suppression value for pixel p of one image ----
__device__ __forceinline__ float compute_jm(const float* __restrict__ base,
                                            int p, int y, int x) {
    float c = base[p];
    float nmax = -3.402823466e38f;
    bool ym = (y > 0), yp = (y < H - 1), xm = (x > 0), xp = (x < W - 1);
    if (ym) {
        const float* r = base + (p - W);
        if (xm) nmax = fmaxf(nmax, r[-1]);
        nmax = fmaxf(nmax, r[0]);
        if (xp) nmax = fmaxf(nmax, r[1]);
    }
    {
        const float* r = base + p;
        if (xm) nmax = fmaxf(nmax, r[-1]);
        if (xp) nmax = fmaxf(nmax, r[1]);
    }
    if (yp) {
        const float* r = base + (p + W);
        if (xm) nmax = fmaxf(nmax, r[-1]);
        nmax = fmaxf(nmax, r[0]);
        if (xp) nmax = fmaxf(nmax, r[1]);
    }
    return (nmax >= c) ? 0.6f * c : c;
}

__device__ __forceinline__ int bucket_of(float s) {
    int braw = (int)(s * 65536.0f);
    braw = braw > 65535 ? 65535 : braw;
    return 65535 - braw;       // ascending bucket = descending score
}

// ---- A1: per-(img,block) coarse histogram ----
__global__ __launch_bounds__(256) void kA1_hist(const float* __restrict__ hm,
                                                uint32* __restrict__ counts) {
    __shared__ uint32 hist[NC];
    int blk = blockIdx.x;             // 0..NPART-1
    int img = blk >> 6;               // /BLOCKS_PER_IMG
    int lblk = blk & (BLOCKS_PER_IMG - 1);
    int t = threadIdx.x;
    hist[t] = 0;
    __syncthreads();
    const float* base = hm + (size_t)img * NPIX;
    int pbase = lblk * BLK_ELEMS;
#pragma unroll
    for (int r = 0; r < 16; ++r) {
        int p = pbase + r * 256 + t;
        int y = p >> LOGW, x = p & (W - 1);
        float jm = compute_jm(base, p, y, x);
        int cb = bucket_of(jm) >> 8;
        atomicAdd(&hist[cb], 1u);
    }
    __syncthreads();
    // layout: counts[img][cb][blk]
    counts[((size_t)img * NC + t) * BLOCKS_PER_IMG + lblk] = hist[t];
}

// ---- A2: per-image exclusive scan of 256*64 = 16384 counts (in place) ----
__global__ __launch_bounds__(256) void kA2_scan(uint32* __restrict__ counts) {
    int img = blockIdx.x;
    int t = threadIdx.x;
    uint32* c = counts + (size_t)img * (NC * BLOCKS_PER_IMG);
    const int CH = (NC * BLOCKS_PER_IMG) / 256;   // 64
    int b0 = t * CH;
    uint32 s = 0;
    for (int i = 0; i < CH; ++i) s += c[b0 + i];
    __shared__ uint32 sums[256];
    sums[t] = s;
    __syncthreads();
    if (t == 0) {
        uint32 run = 0;
        for (int i = 0; i < 256; ++i) { uint32 v = sums[i]; sums[i] = run; run += v; }
    }
    __syncthreads();
    uint32 run = sums[t];
    for (int i = 0; i < CH; ++i) { uint32 v = c[b0 + i]; c[b0 + i] = run; run += v; }
}

// ---- A3: partition into coarse-bucket segments with coalesced writes ----
__global__ __launch_bounds__(256) void kA3_part(const float* __restrict__ hm,
                                                const uint32* __restrict__ scan,
                                                ull* __restrict__ sorted) {
    __shared__ ull skeys[BLK_ELEMS];      // 32KB
    __shared__ uint32 hist[NC], gstart[NC], wofs[NC], sbase[NC], sc[NC];
    int blk = blockIdx.x;
    int img = blk >> 6;
    int lblk = blk & (BLOCKS_PER_IMG - 1);
    int t = threadIdx.x;
    hist[t] = 0;
    sbase[t] = scan[((size_t)img * NC + t) * BLOCKS_PER_IMG + lblk];
    __syncthreads();
    const float* base = hm + (size_t)img * NPIX;
    int pbase = lblk * BLK_ELEMS;
    ull keys[16];
    uint32 cbs[16];
#pragma unroll
    for (int r = 0; r < 16; ++r) {
        int p = pbase + r * 256 + t;
        int y = p >> LOGW, x = p & (W - 1);
        float jm = compute_jm(base, p, y, x);
        uint32 bits = __float_as_uint(jm);
        keys[r] = ((ull)(~bits) << 32) | (uint32)p;
        cbs[r] = (uint32)(bucket_of(jm) >> 8);
        atomicAdd(&hist[cbs[r]], 1u);
    }
    __syncthreads();
    // exclusive scan hist -> gstart
    uint32 v = hist[t];
    sc[t] = v;
    __syncthreads();
    for (int off = 1; off < 256; off <<= 1) {
        uint32 add = (t >= off) ? sc[t - off] : 0u;
        __syncthreads();
        sc[t] += add;
        __syncthreads();
    }
    gstart[t] = sc[t] - v;
    wofs[t] = sc[t] - v;
    __syncthreads();
    // scatter to LDS grouped by coarse bucket (order within group irrelevant; pass B re-sorts)
#pragma unroll
    for (int r = 0; r < 16; ++r) {
        uint32 pos = atomicAdd(&wofs[cbs[r]], 1u);
        skeys[pos] = keys[r];
    }
    __syncthreads();
    // coalesced write-out: contiguous LDS order maps to contiguous per-bucket runs
    ull* sout = sorted + (size_t)img * NPIX;
#pragma unroll
    for (int r = 0; r < 16; ++r) {
        int i = r * 256 + t;
        ull k = skeys[i];
        uint32 bits = ~(uint32)(k >> 32);
        float s = __uint_as_float(bits);
        int cb = bucket_of(s) >> 8;
        sout[sbase[cb] + (uint32)i - gstart[cb]] = k;
    }
}

// ---- B: per-segment fine sort (LDS) + offset gather + coalesced row write ----
__global__ __launch_bounds__(256) void kB_finalize(const ull* __restrict__ sorted,
                                                   const uint32* __restrict__ scan,
                                                   const float* __restrict__ offset,
                                                   float* __restrict__ out) {
    int img = blockIdx.x >> 8;
    int cb = blockIdx.x & (NC - 1);
    int t = threadIdx.x;
    const uint32* sc_img = scan + (size_t)img * (NC * BLOCKS_PER_IMG);
    uint32 cstart = sc_img[cb * BLOCKS_PER_IMG];
    uint32 cend = (cb < NC - 1) ? sc_img[(cb + 1) * BLOCKS_PER_IMG] : (uint32)NPIX;
    int len = (int)(cend - cstart);
    const ull* sin = sorted + (size_t)img * NPIX + cstart;
    const size_t obase2 = (size_t)img * 2 * NPIX;
    float* oseg = out + ((size_t)img * NPIX + cstart) * 3;

    if (len <= 0) return;

    if (len > SEGCAP) {
        // correctness fallback (statistically never taken for these inputs):
        // exact rank by scanning the whole segment from global memory.
        for (int i = t; i < len; i += 256) {
            ull k = sin[i];
            int rank = 0;
            for (int q = 0; q < len; ++q) rank += (sin[q] < k) ? 1 : 0;
            uint32 bits = ~(uint32)(k >> 32);
            float s = __uint_as_float(bits);
            uint32 p0 = (uint32)k;
            int yy = (int)(p0 >> LOGW), xx = (int)(p0 & (W - 1));
            float yo = offset[obase2 + NPIX + p0];
            float xo = offset[obase2 + p0];
            oseg[(size_t)rank * 3 + 0] = (float)yy + yo + 0.5f;
            oseg[(size_t)rank * 3 + 1] = (float)xx + xo + 0.5f;
            oseg[(size_t)rank * 3 + 2] = s;
        }
        return;
    }

    // u0: bufA (keys, 16KB) during sort; reused as rows (24KB) afterwards
    __shared__ ull u0[SEGCAP * 3 / 2];            // 24KB
    __shared__ ull bufB[SEGCAP];                  // 16KB
    __shared__ uint32 fhist[256], fscan[256], fcnt[256];
    ull* bufA = u0;
    float* rows = (float*)u0;

    for (int i = t; i < len; i += 256) bufA[i] = sin[i];
    fhist[t] = 0;
    __syncthreads();
    for (int i = t; i < len; i += 256) {
        ull k = bufA[i];
        float s = __uint_as_float(~(uint32)(k >> 32));
        int f = bucket_of(s) & 255;
        atomicAdd(&fhist[f], 1u);
    }
    __syncthreads();
    // exclusive scan fhist -> fscan, fcnt
    uint32 v = fhist[t];
    fscan[t] = v;
    __syncthreads();
    for (int off = 1; off < 256; off <<= 1) {
        uint32 add = (t >= off) ? fscan[t - off] : 0u;
        __syncthreads();
        fscan[t] += add;
        __syncthreads();
    }
    uint32 excl = fscan[t] - v;
    __syncthreads();
    fscan[t] = excl;
    fcnt[t] = excl;
    __syncthreads();
    // scatter bufA -> bufB grouped by fine bucket
    for (int i = t; i < len; i += 256) {
        ull k = bufA[i];
        float s = __uint_as_float(~(uint32)(k >> 32));
        int f = bucket_of(s) & 255;
        uint32 pos = atomicAdd(&fcnt[f], 1u);
        bufB[pos] = k;
    }
    __syncthreads();   // bufA dead from here; its space becomes `rows`
    // exact rank within fine bucket (keys unique -> deterministic), build rows in LDS
    for (int i = t; i < len; i += 256) {
        ull k = bufB[i];
        uint32 bits = ~(uint32)(k >> 32);
        float s = __uint_as_float(bits);
        int f = bucket_of(s) & 255;
        uint32 gs = fscan[f];
        uint32 ge = gs + fhist[f];
        int rank = 0;
        for (uint32 q = gs; q < ge; ++q) rank += (bufB[q] < k) ? 1 : 0;
        uint32 pos = gs + (uint32)rank;
        uint32 p0 = (uint32)k;
        int yy = (int)(p0 >> LOGW), xx = (int)(p0 & (W - 1));
        float yo = offset[obase2 + NPIX + p0];   // offset[img][1] -> y
        float xo = offset[obase2 + p0];          // offset[img][0] -> x
        rows[pos * 3 + 0] = (float)yy + yo + 0.5f;
        rows[pos * 3 + 1] = (float)xx + xo + 0.5f;
        rows[pos * 3 + 2] = s;
    }
    __syncthreads();
    // coalesced write-out
    int n3 = len * 3;
    for (int i = t; i < n3; i += 256) oseg[i] = rows[i];
}

extern "C" void kernel_launch(void* const* d_in, const int* in_sizes, int n_in,
                              void* d_out, int out_size, void* d_ws, size_t ws_size,
                              hipStream_t stream) {
    const float* hm = (const float*)d_in[0];       // [64, 512, 512] f32
    const float* offset = (const float*)d_in[1];   // [64, 2, 512, 512] f32
    float* out = (float*)d_out;                    // [64, 262144, 3] f32

    const size_t counts_elems = (size_t)NIMG * NC * BLOCKS_PER_IMG;  // 1M uints = 4MB
    uint32* counts = (uint32*)d_ws;
    ull* sorted = (ull*)((char*)d_ws + counts_elems * sizeof(uint32)); // 134MB

    hipMemsetAsync(counts, 0, counts_elems * sizeof(uint32), stream);

    kA1_hist<<<NPART, 256, 0, stream>>>(hm, counts);
    kA2_scan<<<NIMG, 256, 0, stream>>>(counts);
    kA3_part<<<NPART, 256, 0, stream>>>(hm, counts, sorted);
    kB_finalize<<<NIMG * NC, 256, 0, stream>>>(sorted, counts, offset, out);
}

// Round 3
// 744.411 us; speedup vs baseline: 3.1724x; 1.1305x over previous
//
#include <hip/hip_runtime.h>
#include <stdint.h>

#define NIMG 64
#define H 512
#define W 512
#define NPIX (H * W)          // 262144 per image
#define LOGW 9
#define NC 256                 // coarse buckets (top 8 of 16 bucket bits)
#define BLK_ELEMS 4096         // elements per partition block
#define BLOCKS_PER_IMG (NPIX / BLK_ELEMS)   // 64
#define NPART (NIMG * BLOCKS_PER_IMG)       // 4096
#define SEGCAP 2048            // max segment len in LDS (mean 1024, sigma 32; fallback below)

typedef unsigned int uint32;
typedef unsigned long long ull;

// ---- NMS: post-suppression value for pixel p of one image ----
__device__ __forceinline__ float compute_jm(const float* __restrict__ base,
                                            int p, int y, int x) {
    float c = base[p];
    float nmax = -3.402823466e38f;
    bool ym = (y > 0), yp = (y < H - 1), xm = (x > 0), xp = (x < W - 1);
    if (ym) {
        const float* r = base + (p - W);
        if (xm) nmax = fmaxf(nmax, r[-1]);
        nmax = fmaxf(nmax, r[0]);
        if (xp) nmax = fmaxf(nmax, r[1]);
    }
    {
        const float* r = base + p;
        if (xm) nmax = fmaxf(nmax, r[-1]);
        if (xp) nmax = fmaxf(nmax, r[1]);
    }
    if (yp) {
        const float* r = base + (p + W);
        if (xm) nmax = fmaxf(nmax, r[-1]);
        nmax = fmaxf(nmax, r[0]);
        if (xp) nmax = fmaxf(nmax, r[1]);
    }
    return (nmax >= c) ? 0.6f * c : c;
}

__device__ __forceinline__ int bucket_of(float s) {
    int braw = (int)(s * 65536.0f);
    braw = braw > 65535 ? 65535 : braw;
    return 65535 - braw;       // ascending bucket = descending score
}

// ---- A1: per-(img,block) coarse histogram ----
__global__ __launch_bounds__(256) void kA1_hist(const float* __restrict__ hm,
                                                uint32* __restrict__ counts) {
    __shared__ uint32 hist[NC];
    int blk = blockIdx.x;             // 0..NPART-1
    int img = blk >> 6;               // /BLOCKS_PER_IMG
    int lblk = blk & (BLOCKS_PER_IMG - 1);
    int t = threadIdx.x;
    hist[t] = 0;
    __syncthreads();
    const float* base = hm + (size_t)img * NPIX;
    int pbase = lblk * BLK_ELEMS;
#pragma unroll
    for (int r = 0; r < 16; ++r) {
        int p = pbase + r * 256 + t;
        int y = p >> LOGW, x = p & (W - 1);
        float jm = compute_jm(base, p, y, x);
        int cb = bucket_of(jm) >> 8;
        atomicAdd(&hist[cb], 1u);
    }
    __syncthreads();
    counts[((size_t)img * NC + t) * BLOCKS_PER_IMG + lblk] = hist[t];
}

// ---- A2: per-image exclusive scan of 256*64 = 16384 counts (in place) ----
__global__ __launch_bounds__(256) void kA2_scan(uint32* __restrict__ counts) {
    int img = blockIdx.x;
    int t = threadIdx.x;
    uint32* c = counts + (size_t)img * (NC * BLOCKS_PER_IMG);
    const int CH = (NC * BLOCKS_PER_IMG) / 256;   // 64
    int b0 = t * CH;
    uint32 s = 0;
    for (int i = 0; i < CH; ++i) s += c[b0 + i];
    __shared__ uint32 sums[256];
    sums[t] = s;
    __syncthreads();
    if (t == 0) {
        uint32 run = 0;
        for (int i = 0; i < 256; ++i) { uint32 v = sums[i]; sums[i] = run; run += v; }
    }
    __syncthreads();
    uint32 run = sums[t];
    for (int i = 0; i < CH; ++i) { uint32 v = c[b0 + i]; c[b0 + i] = run; run += v; }
}

// ---- A3: partition into coarse-bucket segments with coalesced writes ----
__global__ __launch_bounds__(256) void kA3_part(const float* __restrict__ hm,
                                                const uint32* __restrict__ scan,
                                                ull* __restrict__ sorted) {
    __shared__ ull skeys[BLK_ELEMS];      // 32KB
    __shared__ uint32 hist[NC], gstart[NC], wofs[NC], sbase[NC], sc[NC];
    int blk = blockIdx.x;
    int img = blk >> 6;
    int lblk = blk & (BLOCKS_PER_IMG - 1);
    int t = threadIdx.x;
    hist[t] = 0;
    sbase[t] = scan[((size_t)img * NC + t) * BLOCKS_PER_IMG + lblk];
    __syncthreads();
    const float* base = hm + (size_t)img * NPIX;
    int pbase = lblk * BLK_ELEMS;
    ull keys[16];
    uint32 cbs[16];
#pragma unroll
    for (int r = 0; r < 16; ++r) {
        int p = pbase + r * 256 + t;
        int y = p >> LOGW, x = p & (W - 1);
        float jm = compute_jm(base, p, y, x);
        uint32 bits = __float_as_uint(jm);
        keys[r] = ((ull)(~bits) << 32) | (uint32)p;
        cbs[r] = (uint32)(bucket_of(jm) >> 8);
        atomicAdd(&hist[cbs[r]], 1u);
    }
    __syncthreads();
    uint32 v = hist[t];
    sc[t] = v;
    __syncthreads();
    for (int off = 1; off < 256; off <<= 1) {
        uint32 add = (t >= off) ? sc[t - off] : 0u;
        __syncthreads();
        sc[t] += add;
        __syncthreads();
    }
    gstart[t] = sc[t] - v;
    wofs[t] = sc[t] - v;
    __syncthreads();
#pragma unroll
    for (int r = 0; r < 16; ++r) {
        uint32 pos = atomicAdd(&wofs[cbs[r]], 1u);
        skeys[pos] = keys[r];
    }
    __syncthreads();
    ull* sout = sorted + (size_t)img * NPIX;
#pragma unroll
    for (int r = 0; r < 16; ++r) {
        int i = r * 256 + t;
        ull k = skeys[i];
        uint32 bits = ~(uint32)(k >> 32);
        float s = __uint_as_float(bits);
        int cb = bucket_of(s) >> 8;
        sout[sbase[cb] + (uint32)i - gstart[cb]] = k;
    }
}

// ---- B: per-(img,cb) segment fine sort + offset gather + coalesced row write.
// XCD-pinned mapping: img ≡ (bid & 7) so one image's 2MB offset planes stay
// L2-resident on one XCD while its 256 segments run there back-to-back.
__global__ __launch_bounds__(256) void kB_finalize(const ull* __restrict__ sorted,
                                                   const uint32* __restrict__ scan,
                                                   const float* __restrict__ offset,
                                                   float* __restrict__ out) {
    int bid = blockIdx.x;
    int g = bid >> 3;
    int img = (bid & 7) + 8 * (g >> 8);
    int cb = g & (NC - 1);
    int t = threadIdx.x;
    const uint32* sc_img = scan + (size_t)img * (NC * BLOCKS_PER_IMG);
    uint32 cstart = sc_img[cb * BLOCKS_PER_IMG];
    uint32 cend = (cb < NC - 1) ? sc_img[(cb + 1) * BLOCKS_PER_IMG] : (uint32)NPIX;
    int len = (int)(cend - cstart);
    const ull* sin = sorted + (size_t)img * NPIX + cstart;
    const size_t obase2 = (size_t)img * 2 * NPIX;
    float* oseg = out + ((size_t)img * NPIX + cstart) * 3;

    if (len <= 0) return;

    if (len > SEGCAP) {
        // correctness fallback (statistically never taken for these inputs)
        for (int i = t; i < len; i += 256) {
            ull k = sin[i];
            int rank = 0;
            for (int q = 0; q < len; ++q) rank += (sin[q] < k) ? 1 : 0;
            uint32 bits = ~(uint32)(k >> 32);
            float s = __uint_as_float(bits);
            uint32 p0 = (uint32)k;
            float yo = offset[obase2 + NPIX + p0];
            float xo = offset[obase2 + p0];
            oseg[(size_t)rank * 3 + 0] = (float)(p0 >> LOGW) + yo + 0.5f;
            oseg[(size_t)rank * 3 + 1] = (float)(p0 & (W - 1)) + xo + 0.5f;
            oseg[(size_t)rank * 3 + 2] = s;
        }
        return;
    }

    // rows (24KB) doubles as bufB (first 16KB) — aliasing fenced by barriers
    __shared__ float rows[SEGCAP * 3];
    ull* bufB = (ull*)rows;
    __shared__ uint32 fhist[256], fscan[256], fcnt[256];

    // registers, fully-unrolled static indexing (no scratch)
    ull myk[8];
    int myf[8];
    uint32 mypos[8];

    fhist[t] = 0;
    __syncthreads();
#pragma unroll
    for (int j = 0; j < 8; ++j) {
        int i = t + j * 256;
        if (i < len) {
            ull k = sin[i];
            myk[j] = k;
            float s = __uint_as_float(~(uint32)(k >> 32));
            int f = bucket_of(s) & 255;
            myf[j] = f;
            atomicAdd(&fhist[f], 1u);
        }
    }
    __syncthreads();
    uint32 v = fhist[t];
    fscan[t] = v;
    __syncthreads();
    for (int off = 1; off < 256; off <<= 1) {
        uint32 add = (t >= off) ? fscan[t - off] : 0u;
        __syncthreads();
        fscan[t] += add;
        __syncthreads();
    }
    uint32 excl = fscan[t] - v;
    __syncthreads();
    fscan[t] = excl;
    fcnt[t] = excl;
    __syncthreads();
    // scatter keys (from regs) to bufB grouped by fine bin
#pragma unroll
    for (int j = 0; j < 8; ++j) {
        int i = t + j * 256;
        if (i < len) {
            uint32 pos = atomicAdd(&fcnt[myf[j]], 1u);
            bufB[pos] = myk[j];
        }
    }
    __syncthreads();
    // exact rank of own records within fine bin (keys unique -> deterministic)
#pragma unroll
    for (int j = 0; j < 8; ++j) {
        int i = t + j * 256;
        if (i < len) {
            ull k = myk[j];
            int f = myf[j];
            uint32 gs = fscan[f];
            uint32 ge = gs + fhist[f];
            int rank = 0;
            for (uint32 q = gs; q < ge; ++q) rank += (bufB[q] < k) ? 1 : 0;
            mypos[j] = gs + (uint32)rank;
        }
    }
    __syncthreads();   // all bufB reads complete; space becomes `rows`
#pragma unroll
    for (int j = 0; j < 8; ++j) {
        int i = t + j * 256;
        if (i < len) {
            ull k = myk[j];
            uint32 p0 = (uint32)k;
            float s = __uint_as_float(~(uint32)(k >> 32));
            float yo = offset[obase2 + NPIX + p0];   // offset[img][1] -> y (L2-resident)
            float xo = offset[obase2 + p0];          // offset[img][0] -> x
            uint32 pos = mypos[j];
            rows[pos * 3 + 0] = (float)(p0 >> LOGW) + yo + 0.5f;
            rows[pos * 3 + 1] = (float)(p0 & (W - 1)) + xo + 0.5f;
            rows[pos * 3 + 2] = s;
        }
    }
    __syncthreads();
    int n3 = len * 3;
    for (int i = t; i < n3; i += 256) oseg[i] = rows[i];
}

extern "C" void kernel_launch(void* const* d_in, const int* in_sizes, int n_in,
                              void* d_out, int out_size, void* d_ws, size_t ws_size,
                              hipStream_t stream) {
    const float* hm = (const float*)d_in[0];       // [64, 512, 512] f32
    const float* offset = (const float*)d_in[1];   // [64, 2, 512, 512] f32
    float* out = (float*)d_out;                    // [64, 262144, 3] f32

    const size_t counts_elems = (size_t)NIMG * NC * BLOCKS_PER_IMG;  // 1M uints = 4MB
    uint32* counts = (uint32*)d_ws;
    ull* sorted = (ull*)((char*)d_ws + counts_elems * sizeof(uint32)); // 134MB

    hipMemsetAsync(counts, 0, counts_elems * sizeof(uint32), stream);

    kA1_hist<<<NPART, 256, 0, stream>>>(hm, counts);
    kA2_scan<<<NIMG, 256, 0, stream>>>(counts);
    kA3_part<<<NPART, 256, 0, stream>>>(hm, counts, sorted);
    kB_finalize<<<NIMG * NC, 256, 0, stream>>>(sorted, counts, offset, out);
}